// Round 1
// baseline (1200.064 us; speedup 1.0000x reference)
//
#include <hip/hip_runtime.h>
#include <cstdint>

#define AS1 __attribute__((address_space(1)))
#define AS3 __attribute__((address_space(3)))

typedef __bf16 bf16x8 __attribute__((ext_vector_type(8)));
typedef float f32x4 __attribute__((ext_vector_type(4)));

__device__ __forceinline__ unsigned short f2bf(float f) {
  unsigned u = __float_as_uint(f);
  u += 0x7FFFu + ((u >> 16) & 1u);   // RNE
  return (unsigned short)(u >> 16);
}
__device__ __forceinline__ float bf2f(unsigned short s) {
  return __uint_as_float(((unsigned)s) << 16);
}

// ---------------- fp32 -> bf16 convert (8 elems/thread) ----------------
__global__ void k_f32_to_bf16(const float* __restrict__ in,
                              unsigned short* __restrict__ out, long n8) {
  long i = (long)blockIdx.x * blockDim.x + threadIdx.x;
  if (i >= n8) return;
  const float4* p = (const float4*)in + i * 2;
  float4 a = p[0], b = p[1];
  uint4 o;
  o.x = (unsigned)f2bf(a.x) | ((unsigned)f2bf(a.y) << 16);
  o.y = (unsigned)f2bf(a.z) | ((unsigned)f2bf(a.w) << 16);
  o.z = (unsigned)f2bf(b.x) | ((unsigned)f2bf(b.y) << 16);
  o.w = (unsigned)f2bf(b.z) | ((unsigned)f2bf(b.w) << 16);
  *((uint4*)out + i) = o;
}

// ------------- transpose + convert: out[c*R + r] = bf16(in[r*C + c]) -------------
__global__ void k_transpose_bf16(const float* __restrict__ in,
                                 unsigned short* __restrict__ out, int R, int C) {
  __shared__ float tile[32][33];
  int c0 = blockIdx.x * 32, r0 = blockIdx.y * 32;
  int tx = threadIdx.x & 31, ty = threadIdx.x >> 5;  // 256 threads = 32x8
  #pragma unroll
  for (int i = ty; i < 32; i += 8) tile[i][tx] = in[(long)(r0 + i) * C + c0 + tx];
  __syncthreads();
  #pragma unroll
  for (int i = ty; i < 32; i += 8) out[(long)(c0 + i) * R + r0 + tx] = f2bf(tile[tx][i]);
}

// out_w (H=16,F=1024,Dh=64) -> outw_bt[c=h*64+d][f] bf16 (1024x1024)
__global__ void k_transpose_outw(const float* __restrict__ in,
                                 unsigned short* __restrict__ out) {
  __shared__ float tile[32][33];
  int d0 = blockIdx.x * 32, f0 = blockIdx.y * 32, h = blockIdx.z;
  int tx = threadIdx.x & 31, ty = threadIdx.x >> 5;
  #pragma unroll
  for (int i = ty; i < 32; i += 8)
    tile[i][tx] = in[((long)h * 1024 + f0 + i) * 64 + d0 + tx];
  __syncthreads();
  #pragma unroll
  for (int i = ty; i < 32; i += 8)
    out[((long)h * 64 + d0 + i) * 1024 + f0 + tx] = f2bf(tile[tx][i]);
}

// ---------------- m97-structure bf16 GEMM, 128x128 tile, BK=64, 4 waves ----------------
// A: MxK bf16 row-major; Bt: NxK bf16 row-major (transposed weight). C = A @ Bt^T. N fixed 1024.
enum { EPI_VIS = 0, EPI_QW, EPI_SELF, EPI_Q, EPI_K, EPI_KG };

template <int EPI>
__global__ __launch_bounds__(256) void k_gemm(
    const unsigned short* __restrict__ A, const unsigned short* __restrict__ Bt,
    int M, int K,
    const float* __restrict__ bias,
    const float* __restrict__ mask, const float* __restrict__ QW,
    float* __restrict__ outf, unsigned short* __restrict__ outb,
    unsigned short* __restrict__ ngf) {
  (void)M;
  __shared__ __align__(16) unsigned short As[128 * 64];
  __shared__ __align__(16) unsigned short Bs[128 * 64];
  const int t = threadIdx.x;
  const int l = t & 63, w = t >> 6;
  const int wm = w >> 1, wn = w & 1;
  const long bm0 = (long)blockIdx.y * 128, bn0 = (long)blockIdx.x * 128;

  f32x4 acc[4][4];
  #pragma unroll
  for (int i = 0; i < 4; ++i)
    #pragma unroll
    for (int j = 0; j < 4; ++j) acc[i][j] = (f32x4){0.f, 0.f, 0.f, 0.f};

  const int lrow = l & 15;
  const int lkbase = (l >> 4) * 8;

  for (int k0 = 0; k0 < K; k0 += 64) {
    #pragma unroll
    for (int i = 0; i < 4; ++i) {
      int c = i * 256 + t;
      int row = c >> 3, cc = (c & 7) << 3;
      const unsigned short* ga = A + (bm0 + row) * (long)K + k0 + cc;
      const unsigned short* gb = Bt + (bn0 + row) * (long)K + k0 + cc;
      int ldsoff = __builtin_amdgcn_readfirstlane((i * 256 + w * 64) * 8);
      __builtin_amdgcn_global_load_lds((AS1 void*)ga, (AS3 void*)(As + ldsoff), 16, 0, 0);
      __builtin_amdgcn_global_load_lds((AS1 void*)gb, (AS3 void*)(Bs + ldsoff), 16, 0, 0);
    }
    __syncthreads();
    #pragma unroll
    for (int kk = 0; kk < 2; ++kk) {
      bf16x8 af[4], bfr[4];
      const int lk = kk * 32 + lkbase;
      #pragma unroll
      for (int mf = 0; mf < 4; ++mf)
        af[mf] = *(const bf16x8*)(As + (wm * 64 + mf * 16 + lrow) * 64 + lk);
      #pragma unroll
      for (int nf = 0; nf < 4; ++nf)
        bfr[nf] = *(const bf16x8*)(Bs + (wn * 64 + nf * 16 + lrow) * 64 + lk);
      #pragma unroll
      for (int mf = 0; mf < 4; ++mf)
        #pragma unroll
        for (int nf = 0; nf < 4; ++nf)
          acc[mf][nf] = __builtin_amdgcn_mfma_f32_16x16x32_bf16(af[mf], bfr[nf],
                                                                acc[mf][nf], 0, 0, 0);
    }
    __syncthreads();
  }

  // epilogue: C/D layout col = lane&15, row = (lane>>4)*4 + reg
  #pragma unroll
  for (int mf = 0; mf < 4; ++mf) {
    #pragma unroll
    for (int r = 0; r < 4; ++r) {
      long row = bm0 + wm * 64 + mf * 16 + ((l >> 4) << 2) + r;
      #pragma unroll
      for (int nf = 0; nf < 4; ++nf) {
        long col = bn0 + wn * 64 + nf * 16 + (l & 15);
        float x = acc[mf][nf][r];
        long idx = row * 1024 + col;
        if (EPI == EPI_VIS) {
          x += bias[col];
          x = fmaxf(x, 0.f);
          outf[idx] = x;
          outb[idx] = f2bf(x);
        } else if (EPI == EPI_QW) {
          outf[idx] = x;
        } else if (EPI == EPI_SELF) {
          int b = (int)(row / 36), n = (int)(row % 36);
          x += bias[col] + mask[row] * QW[(long)b * 1024 + col];
          outf[idx] = x;
          outb[idx] = f2bf(x);
          if (n < 20) ngf[((long)b * 20 + n) * 1024 + col] = f2bf(x);
        } else if (EPI == EPI_Q) {
          x += bias[col];
          outb[idx] = f2bf(x);
        } else if (EPI == EPI_K) {
          x += bias[col];
          outb[idx] = f2bf(x);
        } else {  // EPI_KG
          outb[idx] = f2bf(x);
        }
      }
    }
  }
}

// ---------------- row mask: (sum over 1024 != 0) ? 1 : 0, one wave/row ----------------
__global__ void k_mask(const float* __restrict__ vis, float* __restrict__ mask) {
  int row = blockIdx.x * 4 + (threadIdx.x >> 6);
  int l = threadIdx.x & 63;
  const float4* vr = (const float4*)(vis + (long)row * 1024);
  float s = 0.f;
  #pragma unroll
  for (int i = 0; i < 4; ++i) {
    float4 v = vr[l + i * 64];
    s += v.x + v.y + v.z + v.w;
  }
  #pragma unroll
  for (int st = 1; st < 64; st <<= 1) s += __shfl_xor(s, st);
  if (l == 0) mask[row] = (s != 0.f) ? 1.f : 0.f;
}

// ------- pos_logit[b,n,m,h] = log(max(relu(pos_emb[b,n,m,:]·pos_w[:,h]+pos_b[h]),1e-6)) -------
__global__ __launch_bounds__(256) void k_poslogit(const float* __restrict__ pos_emb,
                                                  const float* __restrict__ pos_w,
                                                  const float* __restrict__ pos_b,
                                                  float* __restrict__ plog) {
  __shared__ float wsm[64 * 16];
  __shared__ float bsm[16];
  int t = threadIdx.x;
  for (int i = t; i < 1024; i += 256) wsm[i] = pos_w[i];
  if (t < 16) bsm[t] = pos_b[t];
  __syncthreads();
  long row = (long)blockIdx.x * 16 + (t >> 4);
  int h = t & 15;
  const float4* pr = (const float4*)(pos_emb + row * 64);
  float acc = bsm[h];
  #pragma unroll
  for (int i = 0; i < 16; ++i) {
    float4 v = pr[i];
    acc += v.x * wsm[(i * 4 + 0) * 16 + h];
    acc += v.y * wsm[(i * 4 + 1) * 16 + h];
    acc += v.z * wsm[(i * 4 + 2) * 16 + h];
    acc += v.w * wsm[(i * 4 + 3) * 16 + h];
  }
  acc = fmaxf(acc, 1e-6f);  // relu then clamp collapse to one fmax
  plog[row * 16 + h] = __logf(acc);
}

// ------- fused attention + neighbor + final: block per (b,n), wave per head -------
__global__ __launch_bounds__(1024) void k_attn(
    const unsigned short* __restrict__ qb, const unsigned short* __restrict__ kb,
    const unsigned short* __restrict__ kgb, const float* __restrict__ plog,
    const float* __restrict__ selff, const float* __restrict__ visf,
    const float* __restrict__ outbias, float* __restrict__ out) {
  int bn = blockIdx.x;
  int b = bn / 36;
  int h = threadIdx.x >> 6;
  int l = threadIdx.x & 63;
  long base = (long)bn * 1024 + h * 64 + l;
  float qv = bf2f(qb[base]);
  float aff[20];
  #pragma unroll
  for (int m = 0; m < 20; ++m) {
    float kv = bf2f(kb[((long)(b * 20 + m) << 10) + h * 64 + l]);
    float p = qv * kv;
    #pragma unroll
    for (int st = 1; st < 64; st <<= 1) p += __shfl_xor(p, st);
    aff[m] = p * 0.125f + plog[((long)(bn * 20 + m) << 4) + h];
  }
  float amax = aff[0];
  #pragma unroll
  for (int m = 1; m < 20; ++m) amax = fmaxf(amax, aff[m]);
  float s = 0.f;
  #pragma unroll
  for (int m = 0; m < 20; ++m) {
    aff[m] = __expf(aff[m] - amax);
    s += aff[m];
  }
  float inv = 1.f / s;
  float nb = 0.f;
  #pragma unroll
  for (int m = 0; m < 20; ++m)
    nb += aff[m] * bf2f(kgb[((long)(b * 20 + m) << 10) + h * 64 + l]);
  nb = nb * inv + outbias[h * 64 + l];
  float x = selff[base] + nb;
  out[base] = visf[base] + fmaxf(x, 0.f);
}

extern "C" void kernel_launch(void* const* d_in, const int* in_sizes, int n_in,
                              void* d_out, int out_size, void* d_ws, size_t ws_size,
                              hipStream_t stream) {
  (void)in_sizes; (void)n_in; (void)out_size; (void)ws_size;
  const float* visual   = (const float*)d_in[0];
  const float* pos_emb  = (const float*)d_in[1];
  const float* question = (const float*)d_in[2];
  const float* v2out_w  = (const float*)d_in[3];
  const float* v2out_b  = (const float*)d_in[4];
  const float* self_w   = (const float*)d_in[5];
  const float* self_b   = (const float*)d_in[6];
  const float* q_w      = (const float*)d_in[7];
  const float* q_b      = (const float*)d_in[8];
  const float* k_w      = (const float*)d_in[9];
  const float* k_b      = (const float*)d_in[10];
  const float* pos_w    = (const float*)d_in[11];
  const float* pos_b    = (const float*)d_in[12];
  // d_in[13]=bias_w, d_in[14]=bias_b: constant over softmax axis with adj==1 -> cancels exactly
  const float* out_w    = (const float*)d_in[15];
  const float* out_b    = (const float*)d_in[16];
  float* out = (float*)d_out;

  char* ws = (char*)d_ws;
  size_t off = 0;
  auto alloc = [&](size_t bytes) -> void* {
    off = (off + 255) & ~(size_t)255;
    void* p = ws + off;
    off += bytes;
    return p;
  };

  unsigned short* visual_bf   = (unsigned short*)alloc(18432L * 2048 * 2);
  unsigned short* question_bf = (unsigned short*)alloc(512L * 1024 * 2);
  unsigned short* v2out_wt    = (unsigned short*)alloc(1024L * 2048 * 2);
  unsigned short* self_w1t    = (unsigned short*)alloc(1024L * 1024 * 2);
  unsigned short* self_w2t    = (unsigned short*)alloc(1024L * 1024 * 2);
  unsigned short* q_wt        = (unsigned short*)alloc(1024L * 1024 * 2);
  unsigned short* k_wt        = (unsigned short*)alloc(1024L * 1024 * 2);
  unsigned short* outw_bt     = (unsigned short*)alloc(1024L * 1024 * 2);
  float*          vis_f       = (float*)alloc(18432L * 1024 * 4);
  unsigned short* vis_bf      = (unsigned short*)alloc(18432L * 1024 * 2);
  float*          self_f      = (float*)alloc(18432L * 1024 * 4);
  unsigned short* self_bf     = (unsigned short*)alloc(18432L * 1024 * 2);
  unsigned short* ngf_bf      = (unsigned short*)alloc(10240L * 1024 * 2);
  unsigned short* q_bf        = (unsigned short*)alloc(18432L * 1024 * 2);
  unsigned short* k_bf        = (unsigned short*)alloc(10240L * 1024 * 2);
  unsigned short* kg_bf       = (unsigned short*)alloc(10240L * 1024 * 2);
  float*          plog        = (float*)alloc(368640L * 16 * 4);
  float*          QW          = (float*)alloc(512L * 1024 * 4);
  float*          maskp       = (float*)alloc(18432L * 4);

  // 1) converts
  k_f32_to_bf16<<<18432, 256, 0, stream>>>(visual, visual_bf, 18432L * 2048 / 8);
  k_f32_to_bf16<<<256, 256, 0, stream>>>(question, question_bf, 512L * 1024 / 8);
  // 2) weight transposes (to [n][k] bf16)
  k_transpose_bf16<<<dim3(32, 64), 256, 0, stream>>>(v2out_w, v2out_wt, 2048, 1024);
  k_transpose_bf16<<<dim3(32, 32), 256, 0, stream>>>(self_w, self_w1t, 1024, 1024);
  k_transpose_bf16<<<dim3(32, 32), 256, 0, stream>>>(self_w + 1024L * 1024, self_w2t, 1024, 1024);
  k_transpose_bf16<<<dim3(32, 32), 256, 0, stream>>>(q_w, q_wt, 1024, 1024);
  k_transpose_bf16<<<dim3(32, 32), 256, 0, stream>>>(k_w, k_wt, 1024, 1024);
  k_transpose_outw<<<dim3(2, 32, 16), 256, 0, stream>>>(out_w, outw_bt);

  // 3) vis = relu(visual @ v2out_w + b)
  k_gemm<EPI_VIS><<<dim3(8, 144), 256, 0, stream>>>(visual_bf, v2out_wt, 18432, 2048,
      v2out_b, nullptr, nullptr, vis_f, vis_bf, nullptr);
  // 4) row mask
  k_mask<<<4608, 256, 0, stream>>>(vis_f, maskp);
  // 5) QW = question @ self_w[1024:]
  k_gemm<EPI_QW><<<dim3(8, 4), 256, 0, stream>>>(question_bf, self_w2t, 512, 1024,
      nullptr, nullptr, nullptr, QW, nullptr, nullptr);
  // 6) self_feat = vis @ self_w[:1024] + mask*QW + b   (+ gather ngf)
  k_gemm<EPI_SELF><<<dim3(8, 144), 256, 0, stream>>>(vis_bf, self_w1t, 18432, 1024,
      self_b, maskp, QW, self_f, self_bf, ngf_bf);
  // 7) q = self_feat @ q_w + b
  k_gemm<EPI_Q><<<dim3(8, 144), 256, 0, stream>>>(self_bf, q_wt, 18432, 1024,
      q_b, nullptr, nullptr, nullptr, q_bf, nullptr);
  // 8) k = ngf @ k_w + b
  k_gemm<EPI_K><<<dim3(8, 80), 256, 0, stream>>>(ngf_bf, k_wt, 10240, 1024,
      k_b, nullptr, nullptr, nullptr, k_bf, nullptr);
  // 9) KG = ngf @ out_w (reassociated einsum)
  k_gemm<EPI_KG><<<dim3(8, 80), 256, 0, stream>>>(ngf_bf, outw_bt, 10240, 1024,
      nullptr, nullptr, nullptr, nullptr, kg_bf, nullptr);
  // 10) pos logits
  k_poslogit<<<23040, 256, 0, stream>>>(pos_emb, pos_w, pos_b, plog);
  // 11) fused attention + neighbor + residual
  k_attn<<<18432, 1024, 0, stream>>>(q_bf, k_bf, kg_bf, plog, self_f, vis_f, out_b, out);
}